// Round 9
// baseline (80.432 us; speedup 1.0000x reference)
//
#include <hip/hip_runtime.h>

#define NROWS 8192
#define DIM   256          // elements per row == bytes per row in fp8
#define BHALF 4096
#define NCHUNK 8           // col chunks per 128-row panel (1024 cols each)
#define NREP  4            // DIAGNOSTIC: tile loop repeated; exact result kept
#define SCALE 1.69864358f  // sqrt(2 * log2(e)): dot = sim * log2(e)
#define LN2F  0.69314718f

typedef unsigned char u8;
typedef __attribute__((ext_vector_type(4))) float f32x4;
typedef __attribute__((ext_vector_type(4))) int   i32x4;
typedef __attribute__((ext_vector_type(8))) int   i32x8;

__device__ inline void gload_lds16(const void* g, void* l) {
  __builtin_amdgcn_global_load_lds(
      (const __attribute__((address_space(1))) void*)g,
      (__attribute__((address_space(3))) void*)l, 16, 0, 0);
}

// Kernel 1: row-normalize concat(z_i, z_j), scale by sqrt(2*log2e) so the fp8
// Gram dot = sim*log2e (exp2 instead of exp in the sum). Zeroes out scalar.
__global__ __launch_bounds__(256) void nrm_kernel(const float* __restrict__ zi,
                                                  const float* __restrict__ zj,
                                                  u8* __restrict__ zn8,
                                                  float* __restrict__ out) {
  if (blockIdx.x == 0 && threadIdx.x == 0) out[0] = 0.f;
  const int w = threadIdx.x >> 6, l = threadIdx.x & 63;
  const int row = blockIdx.x * 4 + w;
  const float* src = (row < BHALF) ? zi + (size_t)row * DIM
                                   : zj + (size_t)(row - BHALF) * DIM;
  float4 v = *(const float4*)(src + l * 4);
  float ss = v.x * v.x + v.y * v.y + v.z * v.z + v.w * v.w;
#pragma unroll
  for (int m = 1; m < 64; m <<= 1) ss += __shfl_xor(ss, m);
  float inv = SCALE / fmaxf(sqrtf(ss), 1e-8f);
  int p = __builtin_amdgcn_cvt_pk_fp8_f32(v.x * inv, v.y * inv, 0, false);
  p = __builtin_amdgcn_cvt_pk_fp8_f32(v.z * inv, v.w * inv, p, true);
  *(int*)(zn8 + (size_t)row * DIM + (size_t)l * 4) = p;
}

// Kernel 2: r5 structure with the 8-tile streaming loop run NREP times.
// rsum is zeroed between reps through an opaque (asm-laundered) zero so the
// compiler cannot DCE early reps; final values = last rep = exact r5 result.
// Purpose: T_total = base + (NREP-1)*tiles -> isolates steady-state tile cost,
// and sim becomes visible in rocprof top-5 with true pipe utilizations.
__global__ __launch_bounds__(256, 2) void sim_kernel(const u8* __restrict__ zn8,
                                                     float* __restrict__ partials,
                                                     float* __restrict__ pos) {
  __shared__ __align__(16) u8 Bsm[2][128 * DIM];   // 2 x 32 KB
  __shared__ float plane[2][128];

  const int t = threadIdx.x;
  const int w = t >> 6, l = t & 63;
  const int wa = w >> 1, wb = w & 1;    // wa: col 64-half, wb: panel-row 64-half
  const int rl = l & 15, kg = l >> 4;   // kg = lane's 32B k-block

  const int rp = (int)blockIdx.x >> 3;  // row panel 0..63
  const int ch = (int)blockIdx.x & 7;   // col chunk 0..7
  const int colbase = ch * 1024;        // zn8 row index of first streamed tile

  // stage 128 rows x 256B; linear dest, source chunk inverse-swizzled (salt r&7)
  auto STAGE = [&](int base_row, u8* dst) {
#pragma unroll
    for (int i = 0; i < 8; ++i) {
      int c = i * 256 + t;              // 0..2047 16B-chunks
      int r = c >> 4, cd = c & 15;
      int cs = (cd & 8) | ((cd ^ r) & 7);
      gload_lds16(zn8 + (size_t)(base_row + r) * DIM + (size_t)cs * 16,
                  dst + (size_t)((i * 256 + w * 64) * 16));
    }
  };
  // swizzled fragment read: 32B of row `row`, both k-halves (4 ds_read_b128)
  auto RD2 = [&](const u8* buf, int row, i32x8* dst) {
    const int salt = row & 7;
    const u8* base = buf + row * DIM;
#pragma unroll
    for (int k = 0; k < 2; ++k) {
      i32x4 lo = *(const i32x4*)(base + ((k * 8 + ((kg * 2) ^ salt)) << 4));
      i32x4 hi = *(const i32x4*)(base + ((k * 8 + ((kg * 2 + 1) ^ salt)) << 4));
      dst[k] = __builtin_shufflevector(lo, hi, 0, 1, 2, 3, 4, 5, 6, 7);
    }
  };

  STAGE(rp * 128, &Bsm[0][0]);          // panel -> buf0 (8 loads)
  asm volatile("s_waitcnt vmcnt(0)" ::: "memory");   // panel landed
  __builtin_amdgcn_sched_barrier(0);
  __builtin_amdgcn_s_barrier();
  __builtin_amdgcn_sched_barrier(0);

  i32x8 pb[4][2];                       // panel fragments (B-operand), 64 VGPR
#pragma unroll
  for (int pj = 0; pj < 4; ++pj)
    RD2(&Bsm[0][0], wb * 64 + pj * 16 + rl, pb[pj]);
  asm volatile("s_waitcnt lgkmcnt(0)" ::: "memory");
  __builtin_amdgcn_sched_barrier(0);
  // no barrier: tile0's barrier below also proves all waves finished pb reads

  const int dtile = ((rp >> 3) == ch) ? (rp & 7) : -1;      // diag tile (local)
  const int pg = (rp < 32) ? (rp + 32) : (rp - 32);         // pos col-panel
  const int ptile = ((pg >> 3) == ch) ? (pg & 7) : -1;      // pos tile (local)

  float rsum[4] = {0.f, 0.f, 0.f, 0.f};
  float pv[4]   = {0.f, 0.f, 0.f, 0.f};
  const bool dlane = (wa == wb) && (kg == (rl >> 2));       // self-pair lanes

  float kzero = 0.f;
  asm volatile("" : "+v"(kzero));       // opaque zero: rep-reset is DCE-proof

#pragma unroll 1
  for (int rep = 0; rep < NREP; ++rep) {
    STAGE(colbase, &Bsm[1][0]);         // tile0 -> buf1
    // (buf1's previous readers drained before the last rep's final barrier)

#pragma unroll 2
    for (int ti = 0; ti < 8; ++ti) {
      asm volatile("s_waitcnt vmcnt(0)" ::: "memory");  // tile ti landed (mine)
      __builtin_amdgcn_sched_barrier(0);
      __builtin_amdgcn_s_barrier();     // all waves: ti ready AND ti-1 readers done
      __builtin_amdgcn_sched_barrier(0);

      const u8* Bb = &Bsm[(ti + 1) & 1][0];            // tile ti's buffer
      if (ti < 7) STAGE(colbase + (ti + 1) * 128, &Bsm[ti & 1][0]);  // depth-1

      const bool tdiag = (ti == dtile), tpos = (ti == ptile);

      i32x8 af[2][2];                   // rolling streamed fragments
      RD2(Bb, wa * 64 + rl, af[0]);     // ci=0 (4 ds_reads in flight)
#pragma unroll
      for (int ci = 0; ci < 4; ++ci) {
        if (ci < 3) RD2(Bb, wa * 64 + (ci + 1) * 16 + rl, af[(ci + 1) & 1]);
        if (ci < 3) asm volatile("s_waitcnt lgkmcnt(4)" ::: "memory");
        else        asm volatile("s_waitcnt lgkmcnt(0)" ::: "memory");
        __builtin_amdgcn_sched_barrier(0);

        f32x4 acc[4];
#pragma unroll
        for (int pj = 0; pj < 4; ++pj) acc[pj] = (f32x4){0.f, 0.f, 0.f, 0.f};
        __builtin_amdgcn_s_setprio(1);
#pragma unroll
        for (int k = 0; k < 2; ++k)
#pragma unroll
          for (int pj = 0; pj < 4; ++pj)
            acc[pj] = __builtin_amdgcn_mfma_scale_f32_16x16x128_f8f6f4(
                af[ci & 1][k], pb[pj][k], acc[pj],
                0, 0,                    // cbsz=fp8, blgp=fp8
                0, 0x7f7f7f7f,           // scale_a = 1.0 (e8m0 127)
                0, 0x7f7f7f7f);          // scale_b = 1.0
        __builtin_amdgcn_s_setprio(0);

        // epilogue for this ci: exp2 + lane-local row-sum
#pragma unroll
        for (int pj = 0; pj < 4; ++pj)
#pragma unroll
          for (int jj = 0; jj < 4; ++jj)
            rsum[pj] += __builtin_amdgcn_exp2f(acc[pj][jj]);
        if (tdiag && dlane)              // exact removal of the self term
          rsum[ci] -= __builtin_amdgcn_exp2f(acc[ci][rl & 3]);
        if (tpos && dlane) pv[ci] = acc[ci][rl & 3];
      }
    }

    if (rep < NREP - 1) {
#pragma unroll
      for (int pj = 0; pj < 4; ++pj) rsum[pj] *= kzero;  // exact, opaque reset
    }
  }

  // reduce rsum over the 4 kg lane-groups (bits 4..5), once per block
#pragma unroll
  for (int pj = 0; pj < 4; ++pj) {
    rsum[pj] += __shfl_xor(rsum[pj], 16);
    rsum[pj] += __shfl_xor(rsum[pj], 32);
  }
  if (kg == 0) {
#pragma unroll
    for (int pj = 0; pj < 4; ++pj)
      plane[wa][wb * 64 + pj * 16 + rl] = rsum[pj];
  }
  __syncthreads();
  if (t < 128)
    partials[(size_t)ch * NROWS + rp * 128 + t] = plane[0][t] + plane[1][t];
  if (ptile >= 0 && dlane) {
#pragma unroll
    for (int ci = 0; ci < 4; ++ci)
      pos[rp * 128 + wb * 64 + ci * 16 + rl] = pv[ci] * LN2F;  // back to nats
  }
}

// Kernel 3: per-row lse - pos; block sums folded into one global atomic
// (out pre-zeroed by nrm_kernel; stream order guarantees visibility).
__global__ __launch_bounds__(256) void fin_kernel(const float* __restrict__ partials,
                                                  const float* __restrict__ pos,
                                                  float* __restrict__ out) {
  const int r = blockIdx.x * 256 + threadIdx.x;
  float s = 0.f;
#pragma unroll
  for (int ch = 0; ch < NCHUNK; ++ch) s += partials[(size_t)ch * NROWS + r];
  float v = logf(s) - pos[r];
#pragma unroll
  for (int m = 1; m < 64; m <<= 1) v += __shfl_xor(v, m);
  __shared__ float wsum[4];
  const int w = threadIdx.x >> 6, l = threadIdx.x & 63;
  if (l == 0) wsum[w] = v;
  __syncthreads();
  if (threadIdx.x == 0)
    atomicAdd(out, (wsum[0] + wsum[1] + wsum[2] + wsum[3]) * (1.f / NROWS));
}

extern "C" void kernel_launch(void* const* d_in, const int* in_sizes, int n_in,
                              void* d_out, int out_size, void* d_ws, size_t ws_size,
                              hipStream_t stream) {
  const float* zi = (const float*)d_in[0];
  const float* zj = (const float*)d_in[1];

  u8*    zn8      = (u8*)d_ws;                                              // 2 MB
  float* partials = (float*)((char*)d_ws + (size_t)NROWS * DIM);            // 256 KB
  float* pos      = (float*)((char*)partials + (size_t)NCHUNK * NROWS * 4); // 32 KB
  float* out      = (float*)d_out;

  nrm_kernel<<<NROWS / 4, 256, 0, stream>>>(zi, zj, zn8, out);
  sim_kernel<<<64 * NCHUNK, 256, 0, stream>>>(zn8, partials, pos);
  fin_kernel<<<NROWS / 256, 256, 0, stream>>>(partials, pos, out);
}

// Round 10
// 32.074 us; speedup vs baseline: 2.5077x; 2.5077x over previous
//
#include <hip/hip_runtime.h>

#define NROWS 8192
#define DIM   256          // elements per row == bytes per row in fp8
#define BHALF 4096
#define NCHUNK 8           // col chunks per 128-row panel (1024 cols each)
#define SCALE 1.69864358f  // sqrt(2 * log2(e)): dot = sim * log2(e)
#define LN2F  0.69314718f

typedef unsigned char u8;
typedef __attribute__((ext_vector_type(4))) float f32x4;
typedef __attribute__((ext_vector_type(4))) int   i32x4;
typedef __attribute__((ext_vector_type(8))) int   i32x8;

__device__ inline void gload_lds16(const void* g, void* l) {
  __builtin_amdgcn_global_load_lds(
      (const __attribute__((address_space(1))) void*)g,
      (__attribute__((address_space(3))) void*)l, 16, 0, 0);
}

// Kernel 1: row-normalize concat(z_i, z_j), scale by sqrt(2*log2e) so the fp8
// Gram dot = sim*log2e (exp2 instead of exp in the sum). Zeroes out scalar.
__global__ __launch_bounds__(256) void nrm_kernel(const float* __restrict__ zi,
                                                  const float* __restrict__ zj,
                                                  u8* __restrict__ zn8,
                                                  float* __restrict__ out) {
  if (blockIdx.x == 0 && threadIdx.x == 0) out[0] = 0.f;
  const int w = threadIdx.x >> 6, l = threadIdx.x & 63;
  const int row = blockIdx.x * 4 + w;
  const float* src = (row < BHALF) ? zi + (size_t)row * DIM
                                   : zj + (size_t)(row - BHALF) * DIM;
  float4 v = *(const float4*)(src + l * 4);
  float ss = v.x * v.x + v.y * v.y + v.z * v.z + v.w * v.w;
#pragma unroll
  for (int m = 1; m < 64; m <<= 1) ss += __shfl_xor(ss, m);
  float inv = SCALE / fmaxf(sqrtf(ss), 1e-8f);
  int p = __builtin_amdgcn_cvt_pk_fp8_f32(v.x * inv, v.y * inv, 0, false);
  p = __builtin_amdgcn_cvt_pk_fp8_f32(v.z * inv, v.w * inv, p, true);
  *(int*)(zn8 + (size_t)row * DIM + (size_t)l * 4) = p;
}

// Kernel 2: full-matrix row-sum sweep, r5 skeleton + T15 deferred epilogue:
// acc ping-pong (acc[2][4], static idx); MFMA(ci) issues BEFORE exp2(ci-1),
// so the trans burst executes under the matrix pipe instead of stalling on
// its own cluster (r9 PMC: MFMA 7.4us + VALU 8.3us were ADDITIVE). k=0 MFMA
// takes literal-zero C (no acc zero-init); staging offsets precomputed.
__global__ __launch_bounds__(256, 2) void sim_kernel(const u8* __restrict__ zn8,
                                                     float* __restrict__ partials,
                                                     float* __restrict__ pos) {
  __shared__ __align__(16) u8 Bsm[2][128 * DIM];   // 2 x 32 KB
  __shared__ float plane[2][128];

  const int t = threadIdx.x;
  const int w = t >> 6, l = t & 63;
  const int wa = w >> 1, wb = w & 1;    // wa: col 64-half, wb: panel-row 64-half
  const int rl = l & 15, kg = l >> 4;   // kg = lane's 32B k-block

  const int rp = (int)blockIdx.x >> 3;  // row panel 0..63
  const int ch = (int)blockIdx.x & 7;   // col chunk 0..7
  const int colbase = ch * 1024;        // zn8 row index of first streamed tile

  // precomputed staging offsets (ti-invariant): source inverse-swizzled (r&7)
  int soff[8], doff[8];
#pragma unroll
  for (int i = 0; i < 8; ++i) {
    int c = i * 256 + t;                // 0..2047 16B-chunks
    int r = c >> 4, cd = c & 15;
    int cs = (cd & 8) | ((cd ^ r) & 7);
    soff[i] = r * DIM + cs * 16;
    doff[i] = (i * 256 + w * 64) * 16;
  }
  auto STAGE = [&](int base_row, u8* dst) {
#pragma unroll
    for (int i = 0; i < 8; ++i)
      gload_lds16(zn8 + (size_t)base_row * DIM + soff[i], dst + doff[i]);
  };
  // swizzled fragment read: 32B of row `row`, both k-halves (4 ds_read_b128)
  auto RD2 = [&](const u8* buf, int row, i32x8* dst) {
    const int salt = row & 7;
    const u8* base = buf + row * DIM;
#pragma unroll
    for (int k = 0; k < 2; ++k) {
      i32x4 lo = *(const i32x4*)(base + ((k * 8 + ((kg * 2) ^ salt)) << 4));
      i32x4 hi = *(const i32x4*)(base + ((k * 8 + ((kg * 2 + 1) ^ salt)) << 4));
      dst[k] = __builtin_shufflevector(lo, hi, 0, 1, 2, 3, 4, 5, 6, 7);
    }
  };

  STAGE(rp * 128, &Bsm[0][0]);          // panel -> buf0 (8 loads)
  STAGE(colbase, &Bsm[1][0]);           // tile0 -> buf1 (8 more, 16 in flight)
  asm volatile("s_waitcnt vmcnt(8)" ::: "memory");   // panel landed
  __builtin_amdgcn_sched_barrier(0);
  __builtin_amdgcn_s_barrier();
  __builtin_amdgcn_sched_barrier(0);

  i32x8 pb[4][2];                       // panel fragments (B-operand), 64 VGPR
#pragma unroll
  for (int pj = 0; pj < 4; ++pj)
    RD2(&Bsm[0][0], wb * 64 + pj * 16 + rl, pb[pj]);
  asm volatile("s_waitcnt lgkmcnt(0)" ::: "memory");
  __builtin_amdgcn_sched_barrier(0);
  // no barrier: tile0's barrier below also proves all waves finished pb reads

  const int dtile = ((rp >> 3) == ch) ? (rp & 7) : -1;      // diag tile (local)
  const int pg = (rp < 32) ? (rp + 32) : (rp - 32);         // pos col-panel
  const int ptile = ((pg >> 3) == ch) ? (pg & 7) : -1;      // pos tile (local)

  float rsum[4] = {0.f, 0.f, 0.f, 0.f};
  float pv[4]   = {0.f, 0.f, 0.f, 0.f};
  const bool dlane = (wa == wb) && (kg == (rl >> 2));       // self-pair lanes
  const f32x4 z4 = {0.f, 0.f, 0.f, 0.f};

#pragma unroll 2
  for (int ti = 0; ti < 8; ++ti) {
    asm volatile("s_waitcnt vmcnt(0)" ::: "memory");  // tile ti landed (mine)
    __builtin_amdgcn_sched_barrier(0);
    __builtin_amdgcn_s_barrier();       // all waves: ti ready AND ti-1 readers done
    __builtin_amdgcn_sched_barrier(0);

    const u8* Bb = &Bsm[(ti + 1) & 1][0];            // tile ti's buffer
    if (ti < 7) STAGE(colbase + (ti + 1) * 128, &Bsm[ti & 1][0]);  // depth-1

    const bool tdiag = (ti == dtile), tpos = (ti == ptile);

    // deferred epilogue for column-group cip (operands one cluster old)
    auto EPI = [&](int cip, const f32x4* a) {
#pragma unroll
      for (int pj = 0; pj < 4; ++pj)
#pragma unroll
        for (int jj = 0; jj < 4; ++jj)
          rsum[pj] += __builtin_amdgcn_exp2f(a[pj][jj]);
      if (tdiag && dlane)                // exact removal of the self term
        rsum[cip] -= __builtin_amdgcn_exp2f(a[cip][rl & 3]);
      if (tpos && dlane) pv[cip] = a[cip][rl & 3];
    };

    f32x4 acc[2][4];                    // ping-pong, statically indexed
    i32x8 af[2][2];                     // rolling streamed fragments
    RD2(Bb, wa * 64 + rl, af[0]);       // ci=0 (4 ds_reads in flight)
#pragma unroll
    for (int ci = 0; ci < 4; ++ci) {
      if (ci < 3) RD2(Bb, wa * 64 + (ci + 1) * 16 + rl, af[(ci + 1) & 1]);
      if (ci < 3) asm volatile("s_waitcnt lgkmcnt(4)" ::: "memory");
      else        asm volatile("s_waitcnt lgkmcnt(0)" ::: "memory");
      __builtin_amdgcn_sched_barrier(0);

      __builtin_amdgcn_s_setprio(1);
#pragma unroll
      for (int pj = 0; pj < 4; ++pj)    // k=0: C = literal zero (no acc init)
        acc[ci & 1][pj] = __builtin_amdgcn_mfma_scale_f32_16x16x128_f8f6f4(
            af[ci & 1][0], pb[pj][0], z4,
            0, 0, 0, 0x7f7f7f7f, 0, 0x7f7f7f7f);
#pragma unroll
      for (int pj = 0; pj < 4; ++pj)    // k=1: accumulate
        acc[ci & 1][pj] = __builtin_amdgcn_mfma_scale_f32_16x16x128_f8f6f4(
            af[ci & 1][1], pb[pj][1], acc[ci & 1][pj],
            0, 0, 0, 0x7f7f7f7f, 0, 0x7f7f7f7f);
      __builtin_amdgcn_s_setprio(0);
      __builtin_amdgcn_sched_barrier(0);  // pin: exp2(ci-1) stays AFTER MFMA(ci)

      if (ci > 0) EPI(ci - 1, acc[(ci - 1) & 1]);
    }
    EPI(3, acc[1]);                     // trailing group: overlaps next barrier
  }

  // reduce rsum over the 4 kg lane-groups (bits 4..5), once per block
#pragma unroll
  for (int pj = 0; pj < 4; ++pj) {
    rsum[pj] += __shfl_xor(rsum[pj], 16);
    rsum[pj] += __shfl_xor(rsum[pj], 32);
  }
  if (kg == 0) {
#pragma unroll
    for (int pj = 0; pj < 4; ++pj)
      plane[wa][wb * 64 + pj * 16 + rl] = rsum[pj];
  }
  __syncthreads();
  if (t < 128)
    partials[(size_t)ch * NROWS + rp * 128 + t] = plane[0][t] + plane[1][t];
  if (ptile >= 0 && dlane) {
#pragma unroll
    for (int ci = 0; ci < 4; ++ci)
      pos[rp * 128 + wb * 64 + ci * 16 + rl] = pv[ci] * LN2F;  // back to nats
  }
}

// Kernel 3: per-row lse - pos; block sums folded into one global atomic
// (out pre-zeroed by nrm_kernel; stream order guarantees visibility).
__global__ __launch_bounds__(256) void fin_kernel(const float* __restrict__ partials,
                                                  const float* __restrict__ pos,
                                                  float* __restrict__ out) {
  const int r = blockIdx.x * 256 + threadIdx.x;
  float s = 0.f;
#pragma unroll
  for (int ch = 0; ch < NCHUNK; ++ch) s += partials[(size_t)ch * NROWS + r];
  float v = logf(s) - pos[r];
#pragma unroll
  for (int m = 1; m < 64; m <<= 1) v += __shfl_xor(v, m);
  __shared__ float wsum[4];
  const int w = threadIdx.x >> 6, l = threadIdx.x & 63;
  if (l == 0) wsum[w] = v;
  __syncthreads();
  if (threadIdx.x == 0)
    atomicAdd(out, (wsum[0] + wsum[1] + wsum[2] + wsum[3]) * (1.f / NROWS));
}

extern "C" void kernel_launch(void* const* d_in, const int* in_sizes, int n_in,
                              void* d_out, int out_size, void* d_ws, size_t ws_size,
                              hipStream_t stream) {
  const float* zi = (const float*)d_in[0];
  const float* zj = (const float*)d_in[1];

  u8*    zn8      = (u8*)d_ws;                                              // 2 MB
  float* partials = (float*)((char*)d_ws + (size_t)NROWS * DIM);            // 256 KB
  float* pos      = (float*)((char*)partials + (size_t)NCHUNK * NROWS * 4); // 32 KB
  float* out      = (float*)d_out;

  nrm_kernel<<<NROWS / 4, 256, 0, stream>>>(zi, zj, zn8, out);
  sim_kernel<<<64 * NCHUNK, 256, 0, stream>>>(zn8, partials, pos);
  fin_kernel<<<NROWS / 256, 256, 0, stream>>>(partials, pos, out);
}

// Round 11
// 31.810 us; speedup vs baseline: 2.5285x; 1.0083x over previous
//
#include <hip/hip_runtime.h>

#define NROWS 8192
#define DIM   256          // elements per row == bytes per row in fp8
#define BHALF 4096
#define NCHUNK 8           // col chunks per 128-row panel (1024 cols each)
#define SCALE 1.69864358f  // sqrt(2 * log2(e)): dot = sim * log2(e)
#define LN2F  0.69314718f

typedef unsigned char u8;
typedef __attribute__((ext_vector_type(4))) float f32x4;
typedef __attribute__((ext_vector_type(4))) int   i32x4;
typedef __attribute__((ext_vector_type(8))) int   i32x8;

__device__ inline void gload_lds16(const void* g, void* l) {
  __builtin_amdgcn_global_load_lds(
      (const __attribute__((address_space(1))) void*)g,
      (__attribute__((address_space(3))) void*)l, 16, 0, 0);
}

// exact OCP e4m3fn -> f32 (values here never reach NaN/448)
__device__ inline float fp8_to_f32(int b) {
  const int e = (b >> 3) & 15, m = b & 7;
  float mag = e ? __builtin_bit_cast(float, ((e + 120) << 23) | (m << 20))
                : (float)m * 0x1p-9f;
  return (b & 128) ? -mag : mag;
}

// Kernel 1: row-PAIR normalize (rows r and r+B together): quantize to fp8
// (scaled by sqrt(2*log2e) so Gram dot = sim*log2e), and precompute from the
// DEQUANTIZED values pos[r] (positive-pair dot, in nats) and diag[r]
// (self-dot, log2 units) -- removing all special-case logic from sim.
// Also zeroes rowsum / cnt / out (stream-ordered before sim).
__global__ __launch_bounds__(256) void nrm_kernel(const float* __restrict__ zi,
                                                  const float* __restrict__ zj,
                                                  u8* __restrict__ zn8,
                                                  float* __restrict__ rowsum,
                                                  float* __restrict__ pos,
                                                  float* __restrict__ diag,
                                                  int* __restrict__ cnt,
                                                  float* __restrict__ out) {
  const int t = threadIdx.x, b = blockIdx.x;
  const int gid = b * 256 + t;
  if (gid < NROWS) rowsum[gid] = 0.f;
  if (gid < 64) cnt[gid] = 0;
  if (gid == 0) out[0] = 0.f;

  const int w = t >> 6, l = t & 63;
#pragma unroll
  for (int q = 0; q < 2; ++q) {
    const int p = b * 8 + w * 2 + q;           // pair index 0..4095
    float4 vi = *(const float4*)(zi + (size_t)p * DIM + l * 4);
    float4 vj = *(const float4*)(zj + (size_t)p * DIM + l * 4);
    float ssi = vi.x * vi.x + vi.y * vi.y + vi.z * vi.z + vi.w * vi.w;
    float ssj = vj.x * vj.x + vj.y * vj.y + vj.z * vj.z + vj.w * vj.w;
#pragma unroll
    for (int m = 1; m < 64; m <<= 1) {
      ssi += __shfl_xor(ssi, m);
      ssj += __shfl_xor(ssj, m);
    }
    const float invi = SCALE / fmaxf(sqrtf(ssi), 1e-8f);
    const float invj = SCALE / fmaxf(sqrtf(ssj), 1e-8f);
    int pi = __builtin_amdgcn_cvt_pk_fp8_f32(vi.x * invi, vi.y * invi, 0, false);
    pi = __builtin_amdgcn_cvt_pk_fp8_f32(vi.z * invi, vi.w * invi, pi, true);
    int pj = __builtin_amdgcn_cvt_pk_fp8_f32(vj.x * invj, vj.y * invj, 0, false);
    pj = __builtin_amdgcn_cvt_pk_fp8_f32(vj.z * invj, vj.w * invj, pj, true);
    *(int*)(zn8 + (size_t)p * DIM + l * 4) = pi;
    *(int*)(zn8 + (size_t)(p + BHALF) * DIM + l * 4) = pj;

    // dequantized dot / self-dots (match MFMA values to summation rounding)
    float dot = 0.f, di = 0.f, dj = 0.f;
#pragma unroll
    for (int k2 = 0; k2 < 4; ++k2) {
      const float qi = fp8_to_f32((pi >> (8 * k2)) & 255);
      const float qj = fp8_to_f32((pj >> (8 * k2)) & 255);
      dot += qi * qj; di += qi * qi; dj += qj * qj;
    }
#pragma unroll
    for (int m = 1; m < 64; m <<= 1) {
      dot += __shfl_xor(dot, m);
      di  += __shfl_xor(di, m);
      dj  += __shfl_xor(dj, m);
    }
    if      (l == 0) pos[p] = dot * LN2F;            // nats
    else if (l == 1) pos[p + BHALF] = dot * LN2F;
    else if (l == 2) diag[p] = di;                   // log2 units
    else if (l == 3) diag[p + BHALF] = dj;
  }
}

// Kernel 2: full-matrix row-sum sweep (r10 hot loop, stripped of diag/pos
// special cases) + fence-free fused finish: rowsum accumulated via device
// atomicAdd (L2-coherent); after vmcnt-drain + counter bump, the 8th-arriving
// block per panel reads completed sums via atomic-add-zero, computes
// log(s - exp2(diag)) - pos for its 128 rows, one atomicAdd into out.
__global__ __launch_bounds__(256, 2) void sim_kernel(const u8* __restrict__ zn8,
                                                     float* __restrict__ rowsum,
                                                     const float* __restrict__ pos,
                                                     const float* __restrict__ diag,
                                                     int* __restrict__ cnt,
                                                     float* __restrict__ out) {
  __shared__ __align__(16) u8 Bsm[2][128 * DIM];   // 2 x 32 KB
  __shared__ float plane[2][128];
  __shared__ float wsum[2];
  __shared__ int sfin;

  const int t = threadIdx.x;
  const int w = t >> 6, l = t & 63;
  const int wa = w >> 1, wb = w & 1;    // wa: col 64-half, wb: panel-row 64-half
  const int rl = l & 15, kg = l >> 4;   // kg = lane's 32B k-block

  const int rp = (int)blockIdx.x >> 3;  // row panel 0..63
  const int ch = (int)blockIdx.x & 7;   // col chunk 0..7
  const int colbase = ch * 1024;        // zn8 row index of first streamed tile

  // precomputed staging offsets (ti-invariant): source inverse-swizzled (r&7)
  int soff[8], doff[8];
#pragma unroll
  for (int i = 0; i < 8; ++i) {
    int c = i * 256 + t;                // 0..2047 16B-chunks
    int r = c >> 4, cd = c & 15;
    int cs = (cd & 8) | ((cd ^ r) & 7);
    soff[i] = r * DIM + cs * 16;
    doff[i] = (i * 256 + w * 64) * 16;
  }
  auto STAGE = [&](int base_row, u8* dst) {
#pragma unroll
    for (int i = 0; i < 8; ++i)
      gload_lds16(zn8 + (size_t)base_row * DIM + soff[i], dst + doff[i]);
  };
  // swizzled fragment read: 32B of row `row`, both k-halves (4 ds_read_b128)
  auto RD2 = [&](const u8* buf, int row, i32x8* dst) {
    const int salt = row & 7;
    const u8* base = buf + row * DIM;
#pragma unroll
    for (int k = 0; k < 2; ++k) {
      i32x4 lo = *(const i32x4*)(base + ((k * 8 + ((kg * 2) ^ salt)) << 4));
      i32x4 hi = *(const i32x4*)(base + ((k * 8 + ((kg * 2 + 1) ^ salt)) << 4));
      dst[k] = __builtin_shufflevector(lo, hi, 0, 1, 2, 3, 4, 5, 6, 7);
    }
  };

  STAGE(rp * 128, &Bsm[0][0]);          // panel -> buf0 (8 loads)
  STAGE(colbase, &Bsm[1][0]);           // tile0 -> buf1 (8 more, 16 in flight)
  asm volatile("s_waitcnt vmcnt(8)" ::: "memory");   // panel landed
  __builtin_amdgcn_sched_barrier(0);
  __builtin_amdgcn_s_barrier();
  __builtin_amdgcn_sched_barrier(0);

  i32x8 pb[4][2];                       // panel fragments (B-operand), 64 VGPR
#pragma unroll
  for (int pj = 0; pj < 4; ++pj)
    RD2(&Bsm[0][0], wb * 64 + pj * 16 + rl, pb[pj]);
  asm volatile("s_waitcnt lgkmcnt(0)" ::: "memory");
  __builtin_amdgcn_sched_barrier(0);
  // no barrier: tile0's barrier below also proves all waves finished pb reads

  float rsum[4] = {0.f, 0.f, 0.f, 0.f};
  const f32x4 z4 = {0.f, 0.f, 0.f, 0.f};

  // uniform epilogue: exp2 + lane-local row-sum (no diag/pos cases in-loop)
  auto EPI = [&](const f32x4* a) {
#pragma unroll
    for (int pj = 0; pj < 4; ++pj)
#pragma unroll
      for (int jj = 0; jj < 4; ++jj)
        rsum[pj] += __builtin_amdgcn_exp2f(a[pj][jj]);
  };

#pragma unroll 2
  for (int ti = 0; ti < 8; ++ti) {
    asm volatile("s_waitcnt vmcnt(0)" ::: "memory");  // tile ti landed (mine)
    __builtin_amdgcn_sched_barrier(0);
    __builtin_amdgcn_s_barrier();       // all waves: ti ready AND ti-1 readers done
    __builtin_amdgcn_sched_barrier(0);

    const u8* Bb = &Bsm[(ti + 1) & 1][0];            // tile ti's buffer
    if (ti < 7) STAGE(colbase + (ti + 1) * 128, &Bsm[ti & 1][0]);  // depth-1

    f32x4 acc[2][4];                    // ping-pong, statically indexed
    i32x8 af[2][2];                     // rolling streamed fragments
    RD2(Bb, wa * 64 + rl, af[0]);       // ci=0 (4 ds_reads in flight)
#pragma unroll
    for (int ci = 0; ci < 4; ++ci) {
      if (ci < 3) RD2(Bb, wa * 64 + (ci + 1) * 16 + rl, af[(ci + 1) & 1]);
      if (ci < 3) asm volatile("s_waitcnt lgkmcnt(4)" ::: "memory");
      else        asm volatile("s_waitcnt lgkmcnt(0)" ::: "memory");
      __builtin_amdgcn_sched_barrier(0);

      __builtin_amdgcn_s_setprio(1);
#pragma unroll
      for (int pj = 0; pj < 4; ++pj)    // k=0: C = literal zero (no acc init)
        acc[ci & 1][pj] = __builtin_amdgcn_mfma_scale_f32_16x16x128_f8f6f4(
            af[ci & 1][0], pb[pj][0], z4,
            0, 0, 0, 0x7f7f7f7f, 0, 0x7f7f7f7f);
#pragma unroll
      for (int pj = 0; pj < 4; ++pj)    // k=1: accumulate
        acc[ci & 1][pj] = __builtin_amdgcn_mfma_scale_f32_16x16x128_f8f6f4(
            af[ci & 1][1], pb[pj][1], acc[ci & 1][pj],
            0, 0, 0, 0x7f7f7f7f, 0, 0x7f7f7f7f);
      __builtin_amdgcn_s_setprio(0);
      __builtin_amdgcn_sched_barrier(0);  // pin: exp2(ci-1) stays AFTER MFMA(ci)

      if (ci > 0) EPI(acc[(ci - 1) & 1]);
    }
    EPI(acc[1]);                        // trailing group: overlaps next barrier
  }

  // reduce rsum over the 4 kg lane-groups (bits 4..5), once per block
#pragma unroll
  for (int pj = 0; pj < 4; ++pj) {
    rsum[pj] += __shfl_xor(rsum[pj], 16);
    rsum[pj] += __shfl_xor(rsum[pj], 32);
  }
  if (kg == 0) {
#pragma unroll
    for (int pj = 0; pj < 4; ++pj)
      plane[wa][wb * 64 + pj * 16 + rl] = rsum[pj];
  }
  __syncthreads();

  // ---- fence-free fused finish ----
  if (t < 128)
    atomicAdd(&rowsum[rp * 128 + t], plane[0][t] + plane[1][t]);
  asm volatile("s_waitcnt vmcnt(0)" ::: "memory");   // my atomics at coherence
  __syncthreads();
  if (t == 0) sfin = (atomicAdd(&cnt[rp], 1) == NCHUNK - 1);
  __syncthreads();
  if (sfin) {                           // 8th arrival: all panels' adds landed
    float v = 0.f;
    if (t < 128) {
      const int r = rp * 128 + t;
      float s = atomicAdd(&rowsum[r], 0.f);          // coherent read
      v = logf(s - __builtin_amdgcn_exp2f(diag[r])) - pos[r];
    }
#pragma unroll
    for (int m = 1; m < 64; m <<= 1) v += __shfl_xor(v, m);
    if (l == 0 && t < 128) wsum[w] = v;
    __syncthreads();
    if (t == 0) atomicAdd(out, (wsum[0] + wsum[1]) * (1.f / NROWS));
  }
}

extern "C" void kernel_launch(void* const* d_in, const int* in_sizes, int n_in,
                              void* d_out, int out_size, void* d_ws, size_t ws_size,
                              hipStream_t stream) {
  const float* zi = (const float*)d_in[0];
  const float* zj = (const float*)d_in[1];

  u8*    zn8    = (u8*)d_ws;                                        // 2 MB
  float* rowsum = (float*)((char*)d_ws + (size_t)NROWS * DIM);      // 32 KB
  float* pos    = (float*)((char*)rowsum + (size_t)NROWS * 4);      // 32 KB
  float* diag   = (float*)((char*)pos + (size_t)NROWS * 4);         // 32 KB
  int*   cnt    = (int*)((char*)diag + (size_t)NROWS * 4);          // 256 B
  float* out    = (float*)d_out;

  nrm_kernel<<<512, 256, 0, stream>>>(zi, zj, zn8, rowsum, pos, diag, cnt, out);
  sim_kernel<<<64 * NCHUNK, 256, 0, stream>>>(zn8, rowsum, pos, diag, cnt, out);
}

// Round 12
// 31.708 us; speedup vs baseline: 2.5367x; 1.0032x over previous
//
#include <hip/hip_runtime.h>

#define NROWS 8192
#define DIM   256          // elements per row == bytes per row in fp8
#define BHALF 4096
#define NCHUNK 8           // col chunks per 128-row panel (1024 cols each)
#define SCALE 1.69864358f  // sqrt(2 * log2(e)): dot = sim * log2(e)
#define LN2F  0.69314718f

typedef unsigned char u8;
typedef __attribute__((ext_vector_type(16))) float f32x16;
typedef __attribute__((ext_vector_type(4))) int   i32x4;
typedef __attribute__((ext_vector_type(8))) int   i32x8;

__device__ inline void gload_lds16(const void* g, void* l) {
  __builtin_amdgcn_global_load_lds(
      (const __attribute__((address_space(1))) void*)g,
      (__attribute__((address_space(3))) void*)l, 16, 0, 0);
}

// exact OCP e4m3fn -> f32 (values here never reach NaN/448)
__device__ inline float fp8_to_f32(int b) {
  const int e = (b >> 3) & 15, m = b & 7;
  float mag = e ? __builtin_bit_cast(float, ((e + 120) << 23) | (m << 20))
                : (float)m * 0x1p-9f;
  return (b & 128) ? -mag : mag;
}

// Kernel 1: row-PAIR normalize (rows r and r+B together): quantize to fp8
// (scaled by sqrt(2*log2e) so Gram dot = sim*log2e), and precompute from the
// DEQUANTIZED values pos[r] (positive-pair dot, nats) and diag[r] (self-dot,
// log2 units). Zeroes rowsum / cnt / out (stream-ordered before sim).
__global__ __launch_bounds__(256) void nrm_kernel(const float* __restrict__ zi,
                                                  const float* __restrict__ zj,
                                                  u8* __restrict__ zn8,
                                                  float* __restrict__ rowsum,
                                                  float* __restrict__ pos,
                                                  float* __restrict__ diag,
                                                  int* __restrict__ cnt,
                                                  float* __restrict__ out) {
  const int t = threadIdx.x, b = blockIdx.x;
  const int gid = b * 256 + t;
  if (gid < NROWS) rowsum[gid] = 0.f;
  if (gid < 64) cnt[gid] = 0;
  if (gid == 0) out[0] = 0.f;

  const int w = t >> 6, l = t & 63;
#pragma unroll
  for (int q = 0; q < 2; ++q) {
    const int p = b * 8 + w * 2 + q;           // pair index 0..4095
    float4 vi = *(const float4*)(zi + (size_t)p * DIM + l * 4);
    float4 vj = *(const float4*)(zj + (size_t)p * DIM + l * 4);
    float ssi = vi.x * vi.x + vi.y * vi.y + vi.z * vi.z + vi.w * vi.w;
    float ssj = vj.x * vj.x + vj.y * vj.y + vj.z * vj.z + vj.w * vj.w;
#pragma unroll
    for (int m = 1; m < 64; m <<= 1) {
      ssi += __shfl_xor(ssi, m);
      ssj += __shfl_xor(ssj, m);
    }
    const float invi = SCALE / fmaxf(sqrtf(ssi), 1e-8f);
    const float invj = SCALE / fmaxf(sqrtf(ssj), 1e-8f);
    int pi = __builtin_amdgcn_cvt_pk_fp8_f32(vi.x * invi, vi.y * invi, 0, false);
    pi = __builtin_amdgcn_cvt_pk_fp8_f32(vi.z * invi, vi.w * invi, pi, true);
    int pj = __builtin_amdgcn_cvt_pk_fp8_f32(vj.x * invj, vj.y * invj, 0, false);
    pj = __builtin_amdgcn_cvt_pk_fp8_f32(vj.z * invj, vj.w * invj, pj, true);
    *(int*)(zn8 + (size_t)p * DIM + l * 4) = pi;
    *(int*)(zn8 + (size_t)(p + BHALF) * DIM + l * 4) = pj;

    // dequantized dot / self-dots (match MFMA values to summation rounding)
    float dot = 0.f, di = 0.f, dj = 0.f;
#pragma unroll
    for (int k2 = 0; k2 < 4; ++k2) {
      const float qi = fp8_to_f32((pi >> (8 * k2)) & 255);
      const float qj = fp8_to_f32((pj >> (8 * k2)) & 255);
      dot += qi * qj; di += qi * qi; dj += qj * qj;
    }
#pragma unroll
    for (int m = 1; m < 64; m <<= 1) {
      dot += __shfl_xor(dot, m);
      di  += __shfl_xor(di, m);
      dj  += __shfl_xor(dj, m);
    }
    if      (l == 0) pos[p] = dot * LN2F;            // nats
    else if (l == 1) pos[p + BHALF] = dot * LN2F;
    else if (l == 2) diag[p] = di;                   // log2 units
    else if (l == 3) diag[p + BHALF] = dj;
  }
}

// Kernel 2: full-matrix row-sum sweep on 32x32x64 MX-fp8 MFMA (2x FLOP per
// instr at the same ~35cyc -> MFMA pipe time halves; r9 PMC showed MFMA and
// VALU/trans are ADDITIVE per SIMD, so cutting pipe-cycles is the only lever).
// r11 base: uniform epilogue (diag/pos precomputed in nrm), fence-free atomic
// finish. Wave w owns streamed-tile rows w*32..+32 (A); panel in pb[4][4]
// (B, 128 VGPR). Per tile: 4 kk x 4 pj MFMA, af ping-pong, counted lgkmcnt.
__global__ __launch_bounds__(256, 2) void sim_kernel(const u8* __restrict__ zn8,
                                                     float* __restrict__ rowsum,
                                                     const float* __restrict__ pos,
                                                     const float* __restrict__ diag,
                                                     int* __restrict__ cnt,
                                                     float* __restrict__ out) {
  __shared__ __align__(16) u8 Bsm[2][128 * DIM];   // 2 x 32 KB
  __shared__ float plane[4][128];
  __shared__ float wsum[2];
  __shared__ int sfin;

  const int t = threadIdx.x;
  const int w = t >> 6, l = t & 63;     // w = tile-row strip (32 rows)
  const int n31 = l & 31, kh = l >> 5;  // operand row / k-half

  const int rp = (int)blockIdx.x >> 3;  // row panel 0..63
  const int ch = (int)blockIdx.x & 7;   // col chunk 0..7
  const int colbase = ch * 1024;        // zn8 row index of first streamed tile

  // precomputed staging offsets (ti-invariant): source inverse-swizzled (r&7)
  int soff[8], doff[8];
#pragma unroll
  for (int i = 0; i < 8; ++i) {
    int c = i * 256 + t;                // 0..2047 16B-chunks
    int r = c >> 4, cd = c & 15;
    int cs = (cd & 8) | ((cd ^ r) & 7);
    soff[i] = r * DIM + cs * 16;
    doff[i] = (i * 256 + w * 64) * 16;
  }
  auto STAGE = [&](int base_row, u8* dst) {
#pragma unroll
    for (int i = 0; i < 8; ++i)
      gload_lds16(zn8 + (size_t)base_row * DIM + soff[i], dst + doff[i]);
  };
  // swizzled fragment read for 32x32x64: 32B of row `row`, k-step kk (0..3).
  // logical chunks c0,c0+1 with c0 = kk*4 + kh*2; phys = (c&8)|((c^salt)&7).
  // (verified end-to-end in r8: absmax 0)
  auto RD32 = [&](const u8* buf, int row, int kk) -> i32x8 {
    const int salt = row & 7;
    const u8* base = buf + row * DIM;
    const int c0 = kk * 4 + kh * 2;
    i32x4 lo = *(const i32x4*)(base + (((c0 & 8) | ((c0 ^ salt) & 7)) << 4));
    i32x4 hi = *(const i32x4*)(base + ((((c0 + 1) & 8) | (((c0 + 1) ^ salt) & 7)) << 4));
    return __builtin_shufflevector(lo, hi, 0, 1, 2, 3, 4, 5, 6, 7);
  };

  STAGE(rp * 128, &Bsm[0][0]);          // panel -> buf0 (8 loads)
  STAGE(colbase, &Bsm[1][0]);           // tile0 -> buf1 (8 more, 16 in flight)
  asm volatile("s_waitcnt vmcnt(8)" ::: "memory");   // panel landed
  __builtin_amdgcn_sched_barrier(0);
  __builtin_amdgcn_s_barrier();
  __builtin_amdgcn_sched_barrier(0);

  i32x8 pb[4][4];                       // panel B-frags [pj][kk], 128 VGPR
#pragma unroll
  for (int pj = 0; pj < 4; ++pj)
#pragma unroll
    for (int kk = 0; kk < 4; ++kk)
      pb[pj][kk] = RD32(&Bsm[0][0], pj * 32 + n31, kk);
  asm volatile("s_waitcnt lgkmcnt(0)" ::: "memory");
  __builtin_amdgcn_sched_barrier(0);
  // no barrier: tile0's barrier below also proves all waves finished pb reads

  float rsum[4] = {0.f, 0.f, 0.f, 0.f};

#pragma unroll 2
  for (int ti = 0; ti < 8; ++ti) {
    asm volatile("s_waitcnt vmcnt(0)" ::: "memory");  // tile ti landed (mine)
    __builtin_amdgcn_sched_barrier(0);
    __builtin_amdgcn_s_barrier();       // all waves: ti ready AND ti-1 readers done
    __builtin_amdgcn_sched_barrier(0);

    const u8* Bb = &Bsm[(ti + 1) & 1][0];            // tile ti's buffer
    if (ti < 7) STAGE(colbase + (ti + 1) * 128, &Bsm[ti & 1][0]);  // depth-1

    f32x16 acc[4];
#pragma unroll
    for (int pj = 0; pj < 4; ++pj) acc[pj] = (f32x16)(0.f);

    i32x8 af0 = RD32(Bb, w * 32 + n31, 0);
    i32x8 af1;
#pragma unroll
    for (int kk = 0; kk < 4; ++kk) {
      if (kk < 3) {
        i32x8 nxt = RD32(Bb, w * 32 + n31, kk + 1);
        if (kk & 1) af0 = nxt; else af1 = nxt;
        asm volatile("s_waitcnt lgkmcnt(2)" ::: "memory");
      } else {
        asm volatile("s_waitcnt lgkmcnt(0)" ::: "memory");
      }
      __builtin_amdgcn_sched_barrier(0);
      const i32x8 a = (kk & 1) ? af1 : af0;
      __builtin_amdgcn_s_setprio(1);
#pragma unroll
      for (int pj = 0; pj < 4; ++pj)
        acc[pj] = __builtin_amdgcn_mfma_scale_f32_32x32x64_f8f6f4(
            a, pb[pj][kk], acc[pj],
            0, 0,                        // cbsz=fp8, blgp=fp8
            0, 0x7f7f7f7f,               // scale_a = 1.0 (e8m0 127)
            0, 0x7f7f7f7f);              // scale_b = 1.0
      __builtin_amdgcn_s_setprio(0);
    }

    // uniform epilogue: exp2 + lane-local row-sum (no special cases)
#pragma unroll
    for (int pj = 0; pj < 4; ++pj) {
      float e0 = 0.f, e1 = 0.f, e2 = 0.f, e3 = 0.f;
#pragma unroll
      for (int r16 = 0; r16 < 16; r16 += 4) {
        e0 += __builtin_amdgcn_exp2f(acc[pj][r16]);
        e1 += __builtin_amdgcn_exp2f(acc[pj][r16 + 1]);
        e2 += __builtin_amdgcn_exp2f(acc[pj][r16 + 2]);
        e3 += __builtin_amdgcn_exp2f(acc[pj][r16 + 3]);
      }
      rsum[pj] += (e0 + e1) + (e2 + e3);
    }
  }

  // panel row pj*32+n lives in lanes n and n+32: one xor, then 4-plane sum
#pragma unroll
  for (int pj = 0; pj < 4; ++pj) {
    rsum[pj] += __shfl_xor(rsum[pj], 32);
    if (l < 32) plane[w][pj * 32 + l] = rsum[pj];
  }
  __syncthreads();

  // ---- fence-free fused finish ----
  if (t < 128)
    atomicAdd(&rowsum[rp * 128 + t],
              (plane[0][t] + plane[1][t]) + (plane[2][t] + plane[3][t]));
  asm volatile("s_waitcnt vmcnt(0)" ::: "memory");   // my atomics at coherence
  __syncthreads();
  if (t == 0) sfin = (atomicAdd(&cnt[rp], 1) == NCHUNK - 1);
  __syncthreads();
  if (sfin) {                           // 8th arrival: all panels' adds landed
    float v = 0.f;
    if (t < 128) {
      const int r = rp * 128 + t;
      float s = atomicAdd(&rowsum[r], 0.f);          // coherent read
      v = logf(s - __builtin_amdgcn_exp2f(diag[r])) - pos[r];
    }
#pragma unroll
    for (int m = 1; m < 64; m <<= 1) v += __shfl_xor(v, m);
    if (l == 0 && t < 128) wsum[w] = v;
    __syncthreads();
    if (t == 0) atomicAdd(out, (wsum[0] + wsum[1]) * (1.f / NROWS));
  }
}

extern "C" void kernel_launch(void* const* d_in, const int* in_sizes, int n_in,
                              void* d_out, int out_size, void* d_ws, size_t ws_size,
                              hipStream_t stream) {
  const float* zi = (const float*)d_in[0];
  const float* zj = (const float*)d_in[1];

  u8*    zn8    = (u8*)d_ws;                                        // 2 MB
  float* rowsum = (float*)((char*)d_ws + (size_t)NROWS * DIM);      // 32 KB
  float* pos    = (float*)((char*)rowsum + (size_t)NROWS * 4);      // 32 KB
  float* diag   = (float*)((char*)pos + (size_t)NROWS * 4);         // 32 KB
  int*   cnt    = (int*)((char*)diag + (size_t)NROWS * 4);          // 256 B
  float* out    = (float*)d_out;

  nrm_kernel<<<512, 256, 0, stream>>>(zi, zj, zn8, rowsum, pos, diag, cnt, out);
  sim_kernel<<<64 * NCHUNK, 256, 0, stream>>>(zn8, rowsum, pos, diag, cnt, out);
}